// Round 5
// baseline (78.283 us; speedup 1.0000x reference)
//
#include <hip/hip_runtime.h>

#define NROWS 8192
#define DDIM  64
#define KNN   32
#define MAXIT 100

// alpha/beta arrive as 1-element arrays; robust to int32 or float32 encoding.
__device__ __forceinline__ float scalar_val(const void* p) {
    int iv = *(const int*)p;
    if (iv > -1000000 && iv < 1000000) return (float)iv;
    return *(const float*)p;
}

__device__ __forceinline__ void zero_own_row(float* __restrict__ A, int row, int j) {
    const float4 z4 = make_float4(0.f, 0.f, 0.f, 0.f);
    float4* A4 = (float4*)(A + (size_t)row * NROWS);
    #pragma unroll 8
    for (int i = j; i < NROWS / 4; i += 32) A4[i] = z4;   // 64 float4/lane
}

// One block = 8 rows, half-wave (32 lanes) per row. Two phase orders:
//   parity 0 (store-first):  zeros -> loads/compute -> scatter
//   parity 1 (compute-first): loads/compute -> zeros -> scatter
// Interleaved per-CU so HBM writes and VALU/LLC gathers overlap fleet-wide.
__global__ __launch_bounds__(256, 4) void school_fused_kernel(
    const float* __restrict__ Y,
    const float* __restrict__ semH,
    const float* __restrict__ orthoH,
    const int*   __restrict__ idx,
    const void*  alpha_p,
    const void*  beta_p,
    float* __restrict__ embs,   // N*D
    float* __restrict__ A,      // N*N
    float* __restrict__ Yout)   // N*D
{
    __shared__ float w_s[8][KNN];
    __shared__ int   col_s[8][KNN];

    const int tid  = threadIdx.x;
    const int j    = tid & 31;      // neighbor index within row
    const int r    = tid >> 5;      // row-within-block, 0..7 (half-wave id)
    const int row0 = blockIdx.x * 8;
    const int row  = row0 + r;
    const bool store_first = ((blockIdx.x >> 8) & 1) == 0;

    // ---- store-first blocks: feed HBM immediately, compute later ----
    if (store_first) zero_own_row(A, row, j);

    // ---- Phase 1: distances for (row, neighbor j) ----
    const int col = idx[row * 64 + 1 + j];   // idxa0 = idx[:, 1:33]

    float df = 0.f, dx = 0.f;
    {
        const float4* y0 = (const float4*)(Y + (size_t)row * DDIM);
        const float4* y1 = (const float4*)(Y + (size_t)col * DDIM);
        const float4* o0 = (const float4*)(orthoH + (size_t)row * DDIM);
        const float4* o1 = (const float4*)(orthoH + (size_t)col * DDIM);
        #pragma unroll
        for (int q = 0; q < DDIM / 4; ++q) {
            float4 a = y0[q], b = y1[q];
            float e0 = a.x - b.x, e1 = a.y - b.y, e2 = a.z - b.z, e3 = a.w - b.w;
            df += e0 * e0 + e1 * e1 + e2 * e2 + e3 * e3;
            float4 c = o0[q], d = o1[q];
            float f0 = c.x - d.x, f1 = c.y - d.y, f2 = c.z - d.z, f3 = c.w - d.w;
            dx += f0 * f0 + f1 * f1 + f2 * f2 + f3 * f3;
        }
    }
    df = sqrtf(df + 1e-8f);
    dx = sqrtf(dx + 1e-8f);

    const float alpha = scalar_val(alpha_p);
    const float beta  = scalar_val(beta_p);
    const float ad = -(dx + beta * df) / (2.f * alpha);

    // ---- Phase 2: simplex projection (32 lanes = one row) ----
    float s = ad;
    #pragma unroll
    for (int m = 1; m <= 16; m <<= 1) s += __shfl_xor(s, m, 64);
    const float v0 = ad - s * (1.f / 32.f) + (1.f / 32.f);

    // Newton on piecewise-linear f: tolerance exit (steps hit fp wobble ~1e-8
    // once converged); runs the full 100 like the reference if steps stay big.
    float lam = 0.f;
    #pragma unroll 1
    for (int it = 0; it < MAXIT; ++it) {
        float v1 = v0 - lam;
        float p = v1 > 0.f ? v1 : 0.f;
        float c = v1 > 0.f ? 1.f : 0.f;
        #pragma unroll
        for (int m = 1; m <= 16; m <<= 1) {
            p += __shfl_xor(p, m, 64);
            c += __shfl_xor(c, m, 64);
        }
        float step = (p - 1.f) / fmaxf(c, 1.f);
        lam += step;
        if (__all(fabsf(step) <= 1e-6f ? 1 : 0)) break;
    }
    const float w = fmaxf(v0 - lam, 0.f);

    // ---- Phase 3: dedupe (np fancy-assignment: last j wins); half-wave-local
    col_s[r][j] = col;
    bool dead = false;
    for (int jj = j + 1; jj < 32; ++jj)
        dead |= (col_s[r][jj] == col);
    w_s[r][j] = dead ? 0.f : w;

    // ---- Phase 4: embs_hom[row] = sum_j w_j * semH[col_j]  (coalesced) ----
    {
        float2 acc = make_float2(0.f, 0.f);
        const float2* H2 = (const float2*)semH;
        #pragma unroll 4
        for (int jj = 0; jj < KNN; ++jj) {
            float wv = w_s[r][jj];
            int   c  = col_s[r][jj];
            float2 h = H2[(size_t)c * 32 + j];   // lane j -> dims 2j,2j+1
            acc.x += wv * h.x;
            acc.y += wv * h.y;
        }
        ((float2*)embs)[(size_t)row * 32 + j] = acc;
    }

    // ---- Phase 5: Y passthrough (block's own 8 rows, coalesced, L2-hot) ----
    {
        const float2* Y2 = (const float2*)(Y + (size_t)row0 * DDIM);
        float2* O2 = (float2*)(Yout + (size_t)row0 * DDIM);
        O2[tid] = Y2[tid];
    }

    // ---- compute-first blocks: zeros go out AFTER compute (drain overlaps
    //      the other parity's compute phase) ----
    if (!store_first) zero_own_row(A, row, j);

    // ---- Phase 6: drain own stores, then scatter (lines L2-dirty -> cheap)
    asm volatile("s_waitcnt vmcnt(0)" ::: "memory");
    if (!dead) A[(size_t)row * NROWS + col] = w;
}

extern "C" void kernel_launch(void* const* d_in, const int* in_sizes, int n_in,
                              void* d_out, int out_size, void* d_ws, size_t ws_size,
                              hipStream_t stream) {
    const float* Y      = (const float*)d_in[0];
    const float* semH   = (const float*)d_in[1];
    const float* orthoH = (const float*)d_in[2];
    const int*   idx    = (const int*)d_in[3];
    const void*  alpha  = d_in[4];
    const void*  beta   = d_in[5];

    float* out  = (float*)d_out;
    float* embs = out;                                   // N*D
    float* A    = out + (size_t)NROWS * DDIM;            // N*N
    float* Yout = A + (size_t)NROWS * NROWS;             // N*D

    school_fused_kernel<<<NROWS / 8, 256, 0, stream>>>(
        Y, semH, orthoH, idx, alpha, beta, embs, A, Yout);
}

// Round 6
// 63.486 us; speedup vs baseline: 1.2331x; 1.2331x over previous
//
#include <hip/hip_runtime.h>

#define NROWS 8192
#define DDIM  64
#define KNN   32
#define MAXIT 100

// alpha/beta arrive as 1-element arrays; robust to int32 or float32 encoding.
__device__ __forceinline__ float scalar_val(const void* p) {
    int iv = *(const int*)p;
    if (iv > -1000000 && iv < 1000000) return (float)iv;
    return *(const float*)p;
}

// One block = 8 rows, half-wave (32 lanes) per row.
// - Distances: cooperative coalesced gathers (2 cols per 16-lane group).
// - Newton simplex projection with tolerance early-exit.
// - A-row written ONCE: zeros merged with scatter values (np last-wins).
__global__ __launch_bounds__(256, 4) void school_fused_kernel(
    const float* __restrict__ Y,
    const float* __restrict__ semH,
    const float* __restrict__ orthoH,
    const int*   __restrict__ idx,
    const void*  alpha_p,
    const void*  beta_p,
    float* __restrict__ embs,   // N*D
    float* __restrict__ A,      // N*N
    float* __restrict__ Yout)   // N*D
{
    __shared__ int   col_s[8][KNN];
    __shared__ float w_s[8][KNN];
    __shared__ float ad_s[8][KNN];

    const int tid  = threadIdx.x;
    const int j    = tid & 31;      // lane within half-wave = neighbor slot
    const int r    = tid >> 5;      // row-within-block, 0..7 (half-wave id)
    const int row0 = blockIdx.x * 8;
    const int row  = row0 + r;

    const float alpha = scalar_val(alpha_p);
    const float beta  = scalar_val(beta_p);

    // ---- Phase 0: neighbor ids -> LDS ----
    const int col = idx[row * 64 + 1 + j];   // idxa0 = idx[:, 1:33]
    col_s[r][j] = col;

    // ---- Phase 1: distances, cooperative-coalesced ----
    // Own-row fragment: lane handles float4 #(j&15) of its row (both 16-lane
    // groups hold a full copy of the row).
    const float4* Y4 = (const float4*)Y;
    const float4* O4 = (const float4*)orthoH;
    const int q = j & 15;
    const float4 ownY = Y4[(size_t)row * 16 + q];
    const float4 ownO = O4[(size_t)row * 16 + q];

    #pragma unroll 4
    for (int t = 0; t < 16; ++t) {
        const int c = col_s[r][2 * t + (j >> 4)];   // group 0 -> 2t, group 1 -> 2t+1
        const float4 gY = Y4[(size_t)c * 16 + q];   // 16 lanes x 16B = coalesced row
        const float4 gO = O4[(size_t)c * 16 + q];
        float ex = ownY.x - gY.x, ey = ownY.y - gY.y,
              ez = ownY.z - gY.z, ew = ownY.w - gY.w;
        float dY = ex * ex + ey * ey + ez * ez + ew * ew;
        ex = ownO.x - gO.x; ey = ownO.y - gO.y;
        ez = ownO.z - gO.z; ew = ownO.w - gO.w;
        float dO = ex * ex + ey * ey + ez * ez + ew * ew;
        #pragma unroll
        for (int m = 1; m <= 8; m <<= 1) {          // reduce within 16-lane group
            dY += __shfl_xor(dY, m, 64);
            dO += __shfl_xor(dO, m, 64);
        }
        if ((j & 15) == 0) {
            float dfv = sqrtf(dY + 1e-8f);          // dfi (from Y)
            float dxv = sqrtf(dO + 1e-8f);          // dxi (from ortho_H)
            ad_s[r][2 * t + (j >> 4)] = -(dxv + beta * dfv) / (2.f * alpha);
        }
    }
    const float ad = ad_s[r][j];

    // ---- Phase 2: simplex projection (32 lanes = one row) ----
    float s = ad;
    #pragma unroll
    for (int m = 1; m <= 16; m <<= 1) s += __shfl_xor(s, m, 64);
    const float v0 = ad - s * (1.f / 32.f) + (1.f / 32.f);

    // Newton with tolerance exit (full 100 iters like ref if steps stay big).
    float lam = 0.f;
    #pragma unroll 1
    for (int it = 0; it < MAXIT; ++it) {
        float v1 = v0 - lam;
        float p = v1 > 0.f ? v1 : 0.f;
        float c = v1 > 0.f ? 1.f : 0.f;
        #pragma unroll
        for (int m = 1; m <= 16; m <<= 1) {
            p += __shfl_xor(p, m, 64);
            c += __shfl_xor(c, m, 64);
        }
        float step = (p - 1.f) / fmaxf(c, 1.f);
        lam += step;
        if (__all(fabsf(step) <= 1e-6f ? 1 : 0)) break;
    }
    const float w = fmaxf(v0 - lam, 0.f);

    // ---- Phase 3: dedupe (np fancy-assignment: last j wins) ----
    bool dead = false;
    for (int jj = j + 1; jj < 32; ++jj)
        dead |= (col_s[r][jj] == col);
    w_s[r][j] = dead ? 0.f : w;

    // ---- Phase 4: embs_hom[row] = sum_j w_j * semH[col_j]  (coalesced) ----
    {
        float2 acc = make_float2(0.f, 0.f);
        const float2* H2 = (const float2*)semH;
        #pragma unroll 4
        for (int jj = 0; jj < KNN; ++jj) {
            float wv = w_s[r][jj];
            int   c  = col_s[r][jj];
            float2 h = H2[(size_t)c * 32 + j];
            acc.x += wv * h.x;
            acc.y += wv * h.y;
        }
        ((float2*)embs)[(size_t)row * 32 + j] = acc;
    }

    // ---- Phase 5: Y passthrough ----
    {
        const float2* Y2 = (const float2*)(Y + (size_t)row0 * DDIM);
        float2* O2 = (float2*)(Yout + (size_t)row0 * DDIM);
        O2[tid] = Y2[tid];
    }

    // ---- Phase 6: merged zero+scatter stream for OWN row ----
    // Lane j owns float4 chunks i = 32*s + j (s=0..63); chunk i covers cols
    // [4i,4i+4). For col c: owner=(c>>2)&31, s=c>>7, pos=c&3.
    // Record hits in ascending-jj order (ascending apply = np last-wins).
    unsigned k0 = 0xFFFFFFFFu, k1 = 0xFFFFFFFFu, k2 = 0xFFFFFFFFu, k3 = 0xFFFFFFFFu;
    float f0 = 0.f, f1 = 0.f, f2 = 0.f, f3 = 0.f;
    int nhit = 0;
    #pragma unroll 1
    for (int jj = 0; jj < 32; ++jj) {
        int c = col_s[r][jj];
        if (((c >> 2) & 31) == j) {
            unsigned key = ((unsigned)(c >> 7) << 2) | (unsigned)(c & 3);
            float wv = w_s[r][jj];
            k3 = (nhit == 3) ? key : k3;  f3 = (nhit == 3) ? wv : f3;
            k2 = (nhit == 2) ? key : k2;  f2 = (nhit == 2) ? wv : f2;
            k1 = (nhit == 1) ? key : k1;  f1 = (nhit == 1) ? wv : f1;
            k0 = (nhit == 0) ? key : k0;  f0 = (nhit == 0) ? wv : f0;
            nhit++;
        }
    }

    {
        float4* Arow4 = (float4*)(A + (size_t)row * NROWS);
        #pragma unroll 4
        for (int ss = 0; ss < 64; ++ss) {
            float4 v = make_float4(0.f, 0.f, 0.f, 0.f);
            #define APPLY_SLOT(kk, ff)                                   \
                if ((kk >> 2) == (unsigned)ss) {                         \
                    int p_ = (int)(kk & 3u);                             \
                    v.x = (p_ == 0) ? ff : v.x;                          \
                    v.y = (p_ == 1) ? ff : v.y;                          \
                    v.z = (p_ == 2) ? ff : v.z;                          \
                    v.w = (p_ == 3) ? ff : v.w;                          \
                }
            APPLY_SLOT(k0, f0)
            APPLY_SLOT(k1, f1)
            APPLY_SLOT(k2, f2)
            APPLY_SLOT(k3, f3)
            #undef APPLY_SLOT
            Arow4[(ss << 5) + j] = v;
        }
    }

    // ---- Phase 7: rare overflow (>4 cols map to one lane): fix up after a
    //      drain so the merged chunk store is already visible. ~1e3 lanes
    //      fleet-wide (Poisson), perf-negligible.
    if (nhit > 4) {
        asm volatile("s_waitcnt vmcnt(0)" ::: "memory");
        int cnt = 0;
        for (int jj = 0; jj < 32; ++jj) {
            int c = col_s[r][jj];
            if (((c >> 2) & 31) == j) {
                if (cnt >= 4) {
                    A[(size_t)row * NROWS + c] = w_s[r][jj];
                    asm volatile("s_waitcnt vmcnt(0)" ::: "memory");
                }
                cnt++;
            }
        }
    }
}

extern "C" void kernel_launch(void* const* d_in, const int* in_sizes, int n_in,
                              void* d_out, int out_size, void* d_ws, size_t ws_size,
                              hipStream_t stream) {
    const float* Y      = (const float*)d_in[0];
    const float* semH   = (const float*)d_in[1];
    const float* orthoH = (const float*)d_in[2];
    const int*   idx    = (const int*)d_in[3];
    const void*  alpha  = d_in[4];
    const void*  beta   = d_in[5];

    float* out  = (float*)d_out;
    float* embs = out;                                   // N*D
    float* A    = out + (size_t)NROWS * DDIM;            // N*N
    float* Yout = A + (size_t)NROWS * NROWS;             // N*D

    school_fused_kernel<<<NROWS / 8, 256, 0, stream>>>(
        Y, semH, orthoH, idx, alpha, beta, embs, A, Yout);
}